// Round 9
// baseline (281.846 us; speedup 1.0000x reference)
//
#include <hip/hip_runtime.h>

#define NCACHE 384

__device__ __forceinline__ unsigned int sortable_bits(float f) {
    unsigned int u = __float_as_uint(f);
    return (u & 0x80000000u) ? ~u : (u | 0x80000000u);
}

// 256 threads = 4 waves; wave w handles b = blockIdx.x*4 + w entirely.
__global__ __launch_bounds__(256) void fused_kernel(
    const float*  __restrict__ cache,        // (384,5)
    const float*  __restrict__ refdirs,      // (B,3)
    const float*  __restrict__ normal,       // (B,3)
    const float4* __restrict__ samp_rays4,   // B*96 float4
    const float4* __restrict__ samp_mip4,    // B*32 float4
    float* __restrict__ out, int B)
{
#pragma clang fp contract(off)
    __shared__ float sdx[NCACHE], sdy[NCACHE], sdz[NCACHE], smip[NCACHE];
    __shared__ __align__(16) unsigned int vals[4][NCACHE];  // per-wave sortable value words
    __shared__ unsigned int bitmap[4][12];

    const int tid  = threadIdx.x;
    const int wave = tid >> 6;
    const int lane = tid & 63;
    const int b    = blockIdx.x * 4 + wave;

    // Early-issue pass-through copy loads (hide HBM under the rank loop).
    const int b0 = blockIdx.x * 4;
    const int i0 = tid, i1 = tid + 256;
    const int bb0 = b0 + (i0 >> 7), off0 = i0 & 127;
    const int bb1 = b0 + (i1 >> 7), off1 = i1 & 127;
    const float4 c0 = (off0 < 96) ? samp_rays4[(size_t)bb0 * 96 + off0]
                                  : samp_mip4[(size_t)bb0 * 32 + (off0 - 96)];
    const float4 c1 = (off1 < 96) ? samp_rays4[(size_t)bb1 * 96 + off1]
                                  : samp_mip4[(size_t)bb1 * 32 + (off1 - 96)];

    // Stage cache into LDS (cooperative, once per block)
    for (int m = tid; m < NCACHE; m += 256) {
        sdx[m]  = cache[m * 5 + 0];
        sdy[m]  = cache[m * 5 + 1];
        sdz[m]  = cache[m * 5 + 2];
        smip[m] = cache[m * 5 + 3];
    }
    if (tid < 48) (&bitmap[0][0])[tid] = 0u;

    const float nx = normal[b * 3 + 0], ny = normal[b * 3 + 1], nz = normal[b * 3 + 2];
    const float rx = refdirs[b * 3 + 0], ry = refdirs[b * 3 + 1], rz = refdirs[b * 3 + 2];

    __syncthreads();

    // Scores -> sortable value words (FMA left-chains, bit-exact vs reference;
    // -0.0 canonicalized to +0.0 so ties match float == semantics).
    // Stable u64-key rank == #{j: v_j < v_m} + #{j<m: v_j == v_m}  (32-bit ops only).
    unsigned int vk0 = 0, vk1 = 0;
#pragma unroll
    for (int c = 0; c < 6; ++c) {
        const int m = c * 64 + lane;
        float dx = sdx[m], dy = sdy[m], dz = sdz[m];
        float hemi = __builtin_fmaf(nz, dz, __builtin_fmaf(ny, dy, nx * dx));
        float sim  = __builtin_fmaf(rz, dz, __builtin_fmaf(ry, dy, rx * dx));
        float val  = (hemi > 0.0f) ? -sim : 0.0f;
        val = val + 0.0f;
        const unsigned int sv = sortable_bits(val);
        vals[wave][m] = sv;
        if (c == 0) vk0 = sv;
        if (c == 1) vk1 = sv;
    }
    // Within-wave LDS write->read: DS ops of one wave complete in order; the
    // compiler inserts the lgkmcnt wait. No block barrier needed (per-wave array).

    // LT phase: r += (v_j < v_m) over all 384 j. Uniform uint4 LDS reads feed
    // full-rate 32-bit cmp+addc pairs (2 VALU per key per j, no hazards).
    const uint4* v4 = (const uint4*)&vals[wave][0];
    unsigned int r0 = 0, r1 = 0;
#pragma unroll
    for (int jc = 0; jc < NCACHE / 4; ++jc) {
        const uint4 q = v4[jc];
        asm("v_cmp_lt_u32 vcc, %[va], %[k0]\n\t"
            "v_addc_co_u32 %[r0], vcc, 0, %[r0], vcc\n\t"
            "v_cmp_lt_u32 vcc, %[va], %[k1]\n\t"
            "v_addc_co_u32 %[r1], vcc, 0, %[r1], vcc\n\t"
            "v_cmp_lt_u32 vcc, %[vb], %[k0]\n\t"
            "v_addc_co_u32 %[r0], vcc, 0, %[r0], vcc\n\t"
            "v_cmp_lt_u32 vcc, %[vb], %[k1]\n\t"
            "v_addc_co_u32 %[r1], vcc, 0, %[r1], vcc\n\t"
            "v_cmp_lt_u32 vcc, %[vc], %[k0]\n\t"
            "v_addc_co_u32 %[r0], vcc, 0, %[r0], vcc\n\t"
            "v_cmp_lt_u32 vcc, %[vc], %[k1]\n\t"
            "v_addc_co_u32 %[r1], vcc, 0, %[r1], vcc\n\t"
            "v_cmp_lt_u32 vcc, %[vd], %[k0]\n\t"
            "v_addc_co_u32 %[r0], vcc, 0, %[r0], vcc\n\t"
            "v_cmp_lt_u32 vcc, %[vd], %[k1]\n\t"
            "v_addc_co_u32 %[r1], vcc, 0, %[r1], vcc"
            : [r0] "+v"(r0), [r1] "+v"(r1)
            : [va] "v"(q.x), [vb] "v"(q.y), [vc] "v"(q.z), [vd] "v"(q.w),
              [k0] "v"(vk0), [k1] "v"(vk1)
            : "vcc");
    }

    // EQ phase (tie stability): add #{j < m: v_j == v_m}.
    // key0 (m=lane):    only j<lane, all within c=0 (j<64).
    // key1 (m=lane+64): all j in c=0, plus j in c=1 with (j-64)<lane.
    const unsigned int ulane = (unsigned int)lane;
#pragma unroll
    for (int jc = 0; jc < 16; ++jc) {
        const uint4 q = v4[jc];
        const unsigned int jb = jc * 4;
        r0 += (q.x == vk0 && jb + 0 < ulane) ? 1u : 0u;
        r0 += (q.y == vk0 && jb + 1 < ulane) ? 1u : 0u;
        r0 += (q.z == vk0 && jb + 2 < ulane) ? 1u : 0u;
        r0 += (q.w == vk0 && jb + 3 < ulane) ? 1u : 0u;
        r1 += (q.x == vk1) ? 1u : 0u;
        r1 += (q.y == vk1) ? 1u : 0u;
        r1 += (q.z == vk1) ? 1u : 0u;
        r1 += (q.w == vk1) ? 1u : 0u;
    }
#pragma unroll
    for (int jc = 16; jc < 32; ++jc) {
        const uint4 q = v4[jc];
        const unsigned int jb = (jc - 16) * 4;
        r1 += (q.x == vk1 && jb + 0 < ulane) ? 1u : 0u;
        r1 += (q.y == vk1 && jb + 1 < ulane) ? 1u : 0u;
        r1 += (q.z == vk1 && jb + 2 < ulane) ? 1u : 0u;
        r1 += (q.w == vk1 && jb + 3 < ulane) ? 1u : 0u;
    }

    // Ranks are distinct in [0,384). Output slot = #{selected ranks < r}.
    atomicOr(&bitmap[wave][r0 >> 5], 1u << (r0 & 31));
    atomicOr(&bitmap[wave][r1 >> 5], 1u << (r1 & 31));

    float* out_rays = out;
    float* out_mip  = out + (size_t)B * 768;

    {
        const int wi = (int)r0 >> 5;
        int s = __popc(bitmap[wave][wi] & ((1u << (r0 & 31)) - 1u));
        for (int w = 0; w < wi; ++w) s += __popc(bitmap[wave][w]);
        const size_t rb = (size_t)b * 768 + 384 + (size_t)s * 3;
        out_rays[rb + 0] = sdx[r0];
        out_rays[rb + 1] = sdy[r0];
        out_rays[rb + 2] = sdz[r0];
        out_mip[(size_t)b * 256 + 128 + s] = smip[r0];
    }
    {
        const int wi = (int)r1 >> 5;
        int s = __popc(bitmap[wave][wi] & ((1u << (r1 & 31)) - 1u));
        for (int w = 0; w < wi; ++w) s += __popc(bitmap[wave][w]);
        const size_t rb = (size_t)b * 768 + 384 + (size_t)s * 3;
        out_rays[rb + 0] = sdx[r1];
        out_rays[rb + 1] = sdy[r1];
        out_rays[rb + 2] = sdz[r1];
        out_mip[(size_t)b * 256 + 128 + s] = smip[r1];
    }

    // Pass-through copy stores (loads issued at kernel entry).
    float4* out4     = (float4*)out;
    float4* out_mip4 = (float4*)(out + (size_t)B * 768);
    if (off0 < 96) out4[(size_t)bb0 * 192 + off0] = c0;
    else           out_mip4[(size_t)bb0 * 64 + (off0 - 96)] = c0;
    if (off1 < 96) out4[(size_t)bb1 * 192 + off1] = c1;
    else           out_mip4[(size_t)bb1 * 64 + (off1 - 96)] = c1;
}

extern "C" void kernel_launch(void* const* d_in, const int* in_sizes, int n_in,
                              void* d_out, int out_size, void* d_ws, size_t ws_size,
                              hipStream_t stream) {
    const float* cache       = (const float*)d_in[0];
    const float* refdirs     = (const float*)d_in[1];
    const float* normal      = (const float*)d_in[2];
    const float* samp_rays   = (const float*)d_in[3];
    const float* samp_mipval = (const float*)d_in[4];
    float* out = (float*)d_out;

    const int B = in_sizes[1] / 3;  // 65536

    fused_kernel<<<B / 4, 256, 0, stream>>>(cache, refdirs, normal,
                                            (const float4*)samp_rays,
                                            (const float4*)samp_mipval,
                                            out, B);
}

// Round 10
// 204.907 us; speedup vs baseline: 1.3755x; 1.3755x over previous
//
#include <hip/hip_runtime.h>

#define NCACHE 384

__device__ __forceinline__ unsigned int sortable_bits(float f) {
    unsigned int u = __float_as_uint(f);
    return (u & 0x80000000u) ? ~u : (u | 0x80000000u);
}

struct __align__(16) u64x2 { unsigned long long x, y; };

// 256 threads = 4 waves; wave w handles b = blockIdx.x*4 + w entirely.
// Lane owns keys m0=lane (chunk 0) and m1=64+lane (chunk 1).
// Stable rank decomposition per key m:
//   j in chunks above m : + (v_j <  v_m)          (32-bit cmp_lt, full rate)
//   j in chunks below m : + (v_j <= v_m)          (32-bit cmp_le, full rate)
//   j in m's own chunk  : + (key_j < key_m) u64   (index-embedded, exact ties)
__global__ __launch_bounds__(256) void fused_kernel(
    const float*  __restrict__ cache,        // (384,5)
    const float*  __restrict__ refdirs,      // (B,3)
    const float*  __restrict__ normal,       // (B,3)
    const float4* __restrict__ samp_rays4,   // B*96 float4
    const float4* __restrict__ samp_mip4,    // B*32 float4
    float* __restrict__ out, int B)
{
#pragma clang fp contract(off)
    __shared__ float sdx[NCACHE], sdy[NCACHE], sdz[NCACHE], smip[NCACHE];
    __shared__ __align__(16) unsigned int vals[4][NCACHE];      // sortable value words
    __shared__ __align__(16) unsigned long long keys64[4][128]; // (val<<32)|idx, m<128
    __shared__ unsigned int bitmap[4][12];

    const int tid  = threadIdx.x;
    const int wave = tid >> 6;
    const int lane = tid & 63;
    const int b    = blockIdx.x * 4 + wave;

    // Early-issue pass-through copy loads (hide HBM under the rank loop).
    const int b0 = blockIdx.x * 4;
    const int i0 = tid, i1 = tid + 256;
    const int bb0 = b0 + (i0 >> 7), off0 = i0 & 127;
    const int bb1 = b0 + (i1 >> 7), off1 = i1 & 127;
    const float4 c0 = (off0 < 96) ? samp_rays4[(size_t)bb0 * 96 + off0]
                                  : samp_mip4[(size_t)bb0 * 32 + (off0 - 96)];
    const float4 c1 = (off1 < 96) ? samp_rays4[(size_t)bb1 * 96 + off1]
                                  : samp_mip4[(size_t)bb1 * 32 + (off1 - 96)];

    // Stage cache into LDS (cooperative, once per block)
    for (int m = tid; m < NCACHE; m += 256) {
        sdx[m]  = cache[m * 5 + 0];
        sdy[m]  = cache[m * 5 + 1];
        sdz[m]  = cache[m * 5 + 2];
        smip[m] = cache[m * 5 + 3];
    }
    if (tid < 48) (&bitmap[0][0])[tid] = 0u;

    const float nx = normal[b * 3 + 0], ny = normal[b * 3 + 1], nz = normal[b * 3 + 2];
    const float rx = refdirs[b * 3 + 0], ry = refdirs[b * 3 + 1], rz = refdirs[b * 3 + 2];

    __syncthreads();

    // Scores -> sortable value words (FMA left-chains, bit-exact vs reference;
    // -0.0 canonicalized to +0.0 so ties match float == semantics).
    unsigned int vk0 = 0, vk1 = 0;
#pragma unroll
    for (int c = 0; c < 6; ++c) {
        const int m = c * 64 + lane;
        float dx = sdx[m], dy = sdy[m], dz = sdz[m];
        float hemi = __builtin_fmaf(nz, dz, __builtin_fmaf(ny, dy, nx * dx));
        float sim  = __builtin_fmaf(rz, dz, __builtin_fmaf(ry, dy, rx * dx));
        float val  = (hemi > 0.0f) ? -sim : 0.0f;
        val = val + 0.0f;
        const unsigned int sv = sortable_bits(val);
        vals[wave][m] = sv;
        if (c < 2) keys64[wave][m] = ((unsigned long long)sv << 32) | (unsigned int)m;
        if (c == 0) vk0 = sv;
        if (c == 1) vk1 = sv;
    }
    // Same-wave LDS write->read: DS pipe is in-order per wave; compiler inserts
    // the lgkmcnt wait. No block barrier needed (per-wave arrays). (Proven R8/R9.)

    const unsigned long long K0 = ((unsigned long long)vk0 << 32) | (unsigned int)lane;
    const unsigned long long K1 = ((unsigned long long)vk1 << 32) | (unsigned int)(lane + 64);

    const uint4*  v4 = (const uint4*)&vals[wave][0];
    const u64x2*  k2 = (const u64x2*)&keys64[wave][0];
    unsigned int r0 = 0, r1 = 0;
    unsigned long long sc;

    // Phase A: chunks 2..5 (above both keys): cmp_lt for r0 and r1.
    // Two carry chains (vcc + scratch sgpr pair) to break VCC serialization.
#pragma unroll 8
    for (int i = 32; i < 96; ++i) {
        const uint4 q = v4[i];
        asm("v_cmp_lt_u32 vcc, %[a], %[k0]\n\t"
            "v_cmp_lt_u32 %[sc], %[a], %[k1]\n\t"
            "v_addc_co_u32 %[r0], vcc, 0, %[r0], vcc\n\t"
            "v_addc_co_u32 %[r1], %[sc], 0, %[r1], %[sc]\n\t"
            "v_cmp_lt_u32 vcc, %[b], %[k0]\n\t"
            "v_cmp_lt_u32 %[sc], %[b], %[k1]\n\t"
            "v_addc_co_u32 %[r0], vcc, 0, %[r0], vcc\n\t"
            "v_addc_co_u32 %[r1], %[sc], 0, %[r1], %[sc]\n\t"
            "v_cmp_lt_u32 vcc, %[c], %[k0]\n\t"
            "v_cmp_lt_u32 %[sc], %[c], %[k1]\n\t"
            "v_addc_co_u32 %[r0], vcc, 0, %[r0], vcc\n\t"
            "v_addc_co_u32 %[r1], %[sc], 0, %[r1], %[sc]\n\t"
            "v_cmp_lt_u32 vcc, %[d], %[k0]\n\t"
            "v_cmp_lt_u32 %[sc], %[d], %[k1]\n\t"
            "v_addc_co_u32 %[r0], vcc, 0, %[r0], vcc\n\t"
            "v_addc_co_u32 %[r1], %[sc], 0, %[r1], %[sc]"
            : [r0]"+v"(r0), [r1]"+v"(r1), [sc]"=&s"(sc)
            : [a]"v"(q.x), [b]"v"(q.y), [c]"v"(q.z), [d]"v"(q.w),
              [k0]"v"(vk0), [k1]"v"(vk1)
            : "vcc");
    }

    // Phase B: chunk 0 (below key1): cmp_le for r1.
#pragma unroll 8
    for (int i = 0; i < 16; ++i) {
        const uint4 q = v4[i];
        asm("v_cmp_le_u32 vcc, %[a], %[k1]\n\t"
            "v_cmp_le_u32 %[sc], %[b], %[k1]\n\t"
            "v_addc_co_u32 %[r1], vcc, 0, %[r1], vcc\n\t"
            "v_addc_co_u32 %[r1], %[sc], 0, %[r1], %[sc]\n\t"
            "v_cmp_le_u32 vcc, %[c], %[k1]\n\t"
            "v_cmp_le_u32 %[sc], %[d], %[k1]\n\t"
            "v_addc_co_u32 %[r1], vcc, 0, %[r1], vcc\n\t"
            "v_addc_co_u32 %[r1], %[sc], 0, %[r1], %[sc]"
            : [r1]"+v"(r1), [sc]"=&s"(sc)
            : [a]"v"(q.x), [b]"v"(q.y), [c]"v"(q.z), [d]"v"(q.w), [k1]"v"(vk1)
            : "vcc");
    }

    // Phase C: chunk 1 (above key0): cmp_lt for r0.
#pragma unroll 8
    for (int i = 16; i < 32; ++i) {
        const uint4 q = v4[i];
        asm("v_cmp_lt_u32 vcc, %[a], %[k0]\n\t"
            "v_cmp_lt_u32 %[sc], %[b], %[k0]\n\t"
            "v_addc_co_u32 %[r0], vcc, 0, %[r0], vcc\n\t"
            "v_addc_co_u32 %[r0], %[sc], 0, %[r0], %[sc]\n\t"
            "v_cmp_lt_u32 vcc, %[c], %[k0]\n\t"
            "v_cmp_lt_u32 %[sc], %[d], %[k0]\n\t"
            "v_addc_co_u32 %[r0], vcc, 0, %[r0], vcc\n\t"
            "v_addc_co_u32 %[r0], %[sc], 0, %[r0], %[sc]"
            : [r0]"+v"(r0), [sc]"=&s"(sc)
            : [a]"v"(q.x), [b]"v"(q.y), [c]"v"(q.z), [d]"v"(q.w), [k0]"v"(vk0)
            : "vcc");
    }

    // Phase D: own chunk of key0 (j in [0,64)): exact u64 stable compare.
#pragma unroll 8
    for (int i = 0; i < 32; ++i) {
        const u64x2 kk = k2[i];
        asm("v_cmp_lt_u64 vcc, %[x], %[K]\n\t"
            "v_cmp_lt_u64 %[sc], %[y], %[K]\n\t"
            "v_addc_co_u32 %[r0], vcc, 0, %[r0], vcc\n\t"
            "v_addc_co_u32 %[r0], %[sc], 0, %[r0], %[sc]"
            : [r0]"+v"(r0), [sc]"=&s"(sc)
            : [x]"v"(kk.x), [y]"v"(kk.y), [K]"v"(K0)
            : "vcc");
    }

    // Phase E: own chunk of key1 (j in [64,128)): exact u64 stable compare.
#pragma unroll 8
    for (int i = 32; i < 64; ++i) {
        const u64x2 kk = k2[i];
        asm("v_cmp_lt_u64 vcc, %[x], %[K]\n\t"
            "v_cmp_lt_u64 %[sc], %[y], %[K]\n\t"
            "v_addc_co_u32 %[r1], vcc, 0, %[r1], vcc\n\t"
            "v_addc_co_u32 %[r1], %[sc], 0, %[r1], %[sc]"
            : [r1]"+v"(r1), [sc]"=&s"(sc)
            : [x]"v"(kk.x), [y]"v"(kk.y), [K]"v"(K1)
            : "vcc");
    }

    // Ranks are distinct in [0,384). Output slot = #{selected ranks < r}.
    atomicOr(&bitmap[wave][r0 >> 5], 1u << (r0 & 31));
    atomicOr(&bitmap[wave][r1 >> 5], 1u << (r1 & 31));

    float* out_rays = out;
    float* out_mip  = out + (size_t)B * 768;

    {
        const int wi = (int)r0 >> 5;
        int s = __popc(bitmap[wave][wi] & ((1u << (r0 & 31)) - 1u));
        for (int w = 0; w < wi; ++w) s += __popc(bitmap[wave][w]);
        const size_t rb = (size_t)b * 768 + 384 + (size_t)s * 3;
        out_rays[rb + 0] = sdx[r0];
        out_rays[rb + 1] = sdy[r0];
        out_rays[rb + 2] = sdz[r0];
        out_mip[(size_t)b * 256 + 128 + s] = smip[r0];
    }
    {
        const int wi = (int)r1 >> 5;
        int s = __popc(bitmap[wave][wi] & ((1u << (r1 & 31)) - 1u));
        for (int w = 0; w < wi; ++w) s += __popc(bitmap[wave][w]);
        const size_t rb = (size_t)b * 768 + 384 + (size_t)s * 3;
        out_rays[rb + 0] = sdx[r1];
        out_rays[rb + 1] = sdy[r1];
        out_rays[rb + 2] = sdz[r1];
        out_mip[(size_t)b * 256 + 128 + s] = smip[r1];
    }

    // Pass-through copy stores (loads issued at kernel entry).
    float4* out4     = (float4*)out;
    float4* out_mip4 = (float4*)(out + (size_t)B * 768);
    if (off0 < 96) out4[(size_t)bb0 * 192 + off0] = c0;
    else           out_mip4[(size_t)bb0 * 64 + (off0 - 96)] = c0;
    if (off1 < 96) out4[(size_t)bb1 * 192 + off1] = c1;
    else           out_mip4[(size_t)bb1 * 64 + (off1 - 96)] = c1;
}

extern "C" void kernel_launch(void* const* d_in, const int* in_sizes, int n_in,
                              void* d_out, int out_size, void* d_ws, size_t ws_size,
                              hipStream_t stream) {
    const float* cache       = (const float*)d_in[0];
    const float* refdirs     = (const float*)d_in[1];
    const float* normal      = (const float*)d_in[2];
    const float* samp_rays   = (const float*)d_in[3];
    const float* samp_mipval = (const float*)d_in[4];
    float* out = (float*)d_out;

    const int B = in_sizes[1] / 3;  // 65536

    fused_kernel<<<B / 4, 256, 0, stream>>>(cache, refdirs, normal,
                                            (const float4*)samp_rays,
                                            (const float4*)samp_mipval,
                                            out, B);
}